// Round 13
// baseline (1712.316 us; speedup 1.0000x reference)
//
#include <hip/hip_runtime.h>
#include <hip/hip_cooperative_groups.h>

namespace cg = cooperative_groups;

// Integrator (scaling & squaring) for vel [16,2,512,512] f32, with logdet-Jacobian.
// Decoupled schedule + packed f16x4 records (disp.y, disp.x, ldjac, pad).
// ROUND-13: steps K2..K7 + FINAL fused into ONE persistent cooperative kernel
// (grid.sync() between phases). 2048 blocks, XCD-pinned: block b serves images
// {2*(b&7), 2*(b&7)+1} every phase -> phase outputs stay in that XCD's L2.
// Dispatches: INIT_FUSED (regular) -> INTEGRATE_COOP (cooperative).
// Buffers: A = d_out raw bytes (32MB), B = ws (32MB). FINAL: B -> planar f32 d_out.

#define NB 16
#define HH 512
#define WW 512
#define HW (HH * WW)          // 262144 = 1<<18
#define TOT (NB * HW)         // 4194304
#define EPS 0.0078125f        // 2^-7
#define DISP_ELEMS (NB * 2 * HW)   // 8388608 (f32 elems of final planar disp)
#define SC (512.0f / 511.0f)

typedef _Float16 f16;
typedef _Float16 f16x4 __attribute__((ext_vector_type(4)));

struct Samp {
    int i00, i01, i10, i11;   // clamped plane offsets (y*W+x)
    float w00, w01, w10, w11; // bilinear weights with OOB folded to 0
};

__device__ __forceinline__ Samp make_samp(float sy, float sx) {
    float fy = floorf(sy), fx = floorf(sx);
    float wy = sy - fy, wx = sx - fx;
    int y0 = (int)fy, x0 = (int)fx;
    int y1 = y0 + 1, x1 = x0 + 1;
    bool xv0 = (unsigned)x0 < (unsigned)WW;
    bool xv1 = (unsigned)x1 < (unsigned)WW;
    bool yv0 = (unsigned)y0 < (unsigned)HH;
    bool yv1 = (unsigned)y1 < (unsigned)HH;
    int xc0 = min(max(x0, 0), WW - 1), xc1 = min(max(x1, 0), WW - 1);
    int yc0 = min(max(y0, 0), HH - 1), yc1 = min(max(y1, 0), HH - 1);
    Samp s;
    s.i00 = yc0 * WW + xc0; s.i01 = yc0 * WW + xc1;
    s.i10 = yc1 * WW + xc0; s.i11 = yc1 * WW + xc1;
    float omwx = 1.0f - wx, omwy = 1.0f - wy;
    s.w00 = (xv0 && yv0) ? omwx * omwy : 0.0f;
    s.w01 = (xv1 && yv0) ? wx * omwy   : 0.0f;
    s.w10 = (xv0 && yv1) ? omwx * wy   : 0.0f;
    s.w11 = (xv1 && yv1) ? wx * wy     : 0.0f;
    return s;
}

// XCD-remapped index for the regular init dispatch (16384 blocks round-robin).
__device__ __forceinline__ int remap_idx() {
    int bid = blockIdx.x;
    int task = ((bid & 7) << 11) | (bid >> 3);
    return task * 256 + threadIdx.x;
}

// emulate the fp16 store+load rounding of disp0 = eps*v
__device__ __forceinline__ float rnd16(float v) { return (float)(f16)v; }

// INIT_FUSED: ldjac0 (sobel logdet series) + disp1 (corners gathered from vel,
// fp16 rounding of disp0 emulated). Writes packed record (disp1, ldjac0).
__global__ void __launch_bounds__(256) init_fused(const float* __restrict__ vel,
                                                  f16x4* __restrict__ rdst) {
    int idx = remap_idx();
    int n = idx >> 18;
    int rem = idx & (HW - 1);
    int y = rem >> 9, x = rem & (WW - 1);

    const float* v0 = vel + (size_t)n * 2 * HW;  // vel_y
    const float* v1 = v0 + HW;                   // vel_x

    int ym = max(y - 1, 0), yp = min(y + 1, HH - 1);
    int xm = max(x - 1, 0), xp = min(x + 1, WW - 1);
    int rmm = ym * WW + xm, rm0 = ym * WW + x, rmp = ym * WW + xp;
    int r0m = y * WW + xm,  r00 = y * WW + x,  r0p = y * WW + xp;
    int rpm = yp * WW + xm, rp0 = yp * WW + x, rpp = yp * WW + xp;

    float a, b, c, d;
    {
        float tmm = v0[rmm], tm0 = v0[rm0], tmp = v0[rmp];
        float t0m = v0[r0m],                t0p = v0[r0p];
        float tpm = v0[rpm], tp0 = v0[rp0], tpp = v0[rpp];
        a = 0.125f * ((tpm + 2.0f * tp0 + tpp) - (tmm + 2.0f * tm0 + tmp));
        b = 0.125f * ((tmp + 2.0f * t0p + tpp) - (tmm + 2.0f * t0m + tpm));
    }
    {
        float tmm = v1[rmm], tm0 = v1[rm0], tmp = v1[rmp];
        float t0m = v1[r0m],                t0p = v1[r0p];
        float tpm = v1[rpm], tp0 = v1[rp0], tpp = v1[rpp];
        c = 0.125f * ((tpm + 2.0f * tp0 + tpp) - (tmm + 2.0f * tm0 + tmp));
        d = 0.125f * ((tmp + 2.0f * t0p + tpp) - (tmm + 2.0f * t0m + tpm));
    }

    float xa = a, xb = b, xc = c, xd = d;
    float ld = EPS * (xa + xd);
    float na = xa * a + xb * c, nb = xa * b + xb * d;
    float nc = xc * a + xd * c, nd = xc * b + xd * d;
    xa = na; xb = nb; xc = nc; xd = nd;
    ld -= (EPS * EPS) * (xa + xd) * 0.5f;
    na = xa * a + xb * c; nb = xa * b + xb * d;
    nc = xc * a + xd * c; nd = xc * b + xd * d;
    xa = na; xb = nb; xc = nc; xd = nd;
    ld += (EPS * EPS * EPS) * (xa + xd) * (1.0f / 3.0f);
    na = xa * a + xb * c;
    nd = xc * b + xd * d;
    ld -= (EPS * EPS * EPS * EPS) * (na + nd) * 0.25f;

    float d0 = rnd16(EPS * v0[r00]);
    float d1 = rnd16(EPS * v1[r00]);

    float sy = fmaf((float)y + d0, SC, -0.5f);
    float sx = fmaf((float)x + d1, SC, -0.5f);
    Samp s = make_samp(sy, sx);

    float g00x = rnd16(EPS * v0[s.i00]), g00y = rnd16(EPS * v1[s.i00]);
    float g01x = rnd16(EPS * v0[s.i01]), g01y = rnd16(EPS * v1[s.i01]);
    float g10x = rnd16(EPS * v0[s.i10]), g10y = rnd16(EPS * v1[s.i10]);
    float g11x = rnd16(EPS * v0[s.i11]), g11y = rnd16(EPS * v1[s.i11]);

    float nd0 = d0 + s.w00 * g00x + s.w01 * g01x + s.w10 * g10x + s.w11 * g11x;
    float nd1 = d1 + s.w00 * g00y + s.w01 * g01y + s.w10 * g10y + s.w11 * g11y;

    f16x4 rec;
    rec.x = (f16)nd0; rec.y = (f16)nd1; rec.z = (f16)ld; rec.w = (f16)0.0f;
    rdst[(size_t)n * HW + rem] = rec;
}

// one packed step at global pixel index idx: disp_{k+1} + ldjac_k (shared samp)
__device__ __forceinline__ void step_body(const f16x4* __restrict__ rsrc,
                                          f16x4* __restrict__ rdst, int idx) {
    int n = idx >> 18;
    int rem = idx & (HW - 1);
    int y = rem >> 9, x = rem & (WW - 1);

    const f16x4* rp = rsrc + (size_t)n * HW;

    f16x4 rv = rp[rem];
    float d0 = (float)rv.x, d1 = (float)rv.y, l = (float)rv.z;

    float sy = fmaf((float)y + d0, SC, -0.5f);
    float sx = fmaf((float)x + d1, SC, -0.5f);
    Samp s = make_samp(sy, sx);

    f16x4 g00 = rp[s.i00], g01 = rp[s.i01], g10 = rp[s.i10], g11 = rp[s.i11];

    float nd0 = d0 + s.w00 * (float)g00.x + s.w01 * (float)g01.x
                   + s.w10 * (float)g10.x + s.w11 * (float)g11.x;
    float nd1 = d1 + s.w00 * (float)g00.y + s.w01 * (float)g01.y
                   + s.w10 * (float)g10.y + s.w11 * (float)g11.y;
    float nl  = l  + s.w00 * (float)g00.z + s.w01 * (float)g01.z
                   + s.w10 * (float)g10.z + s.w11 * (float)g11.z;

    f16x4 w;
    w.x = (f16)nd0; w.y = (f16)nd1; w.z = (f16)nl; w.w = (f16)0.0f;
    rdst[(size_t)n * HW + rem] = w;
}

// persistent cooperative kernel: 6 packed steps (grid.sync between) + FINAL.
// 2048 blocks; block b XCD-pinned to images {2*(b&7), 2*(b&7)+1}; 8 tasks/phase.
__global__ void __launch_bounds__(256, 8) integrate_coop(f16x4* __restrict__ rA,
                                                         f16x4* __restrict__ rB,
                                                         float* __restrict__ doutp,
                                                         float* __restrict__ loutp) {
    cg::grid_group grid = cg::this_grid();

    int b = blockIdx.x;
    int xcd = b & 7;
    int sub = b >> 3;                      // 0..255

    const f16x4* src = rB;
    f16x4* dst = rA;

#pragma unroll 1
    for (int s = 0; s < 6; ++s) {
#pragma unroll 1
        for (int j = 0; j < 8; ++j) {
            int task = (xcd << 11) | (sub + (j << 8));   // within this XCD's 2 images
            step_body(src, dst, task * 256 + threadIdx.x);
        }
        grid.sync();
        const f16x4* t = src; src = dst; dst = (f16x4*)t;
    }
    // after 6 swaps src == rB (disp7, ldjac6); FINAL: ldjac7 + planar f32 out
#pragma unroll 1
    for (int j = 0; j < 8; ++j) {
        int task = (xcd << 11) | (sub + (j << 8));
        int idx = task * 256 + threadIdx.x;
        int n = idx >> 18;
        int rem = idx & (HW - 1);
        int y = rem >> 9, x = rem & (WW - 1);

        const f16x4* rp = src + (size_t)n * HW;
        f16x4 rv = rp[rem];
        float d0 = (float)rv.x, d1 = (float)rv.y, l = (float)rv.z;

        float sy = fmaf((float)y + d0, SC, -0.5f);
        float sx = fmaf((float)x + d1, SC, -0.5f);
        Samp s = make_samp(sy, sx);

        f16x4 g00 = rp[s.i00], g01 = rp[s.i01], g10 = rp[s.i10], g11 = rp[s.i11];
        float nl = l + s.w00 * (float)g00.z + s.w01 * (float)g01.z
                     + s.w10 * (float)g10.z + s.w11 * (float)g11.z;

        float* pd = doutp + (size_t)n * 2 * HW;
        pd[rem]      = d0;
        pd[HW + rem] = d1;
        loutp[(size_t)n * HW + rem] = nl;
    }
}

extern "C" void kernel_launch(void* const* d_in, const int* in_sizes, int n_in,
                              void* d_out, int out_size, void* d_ws, size_t ws_size,
                              hipStream_t stream) {
    const float* vel = (const float*)d_in[0];
    float* out = (float*)d_out;
    float* lout = out + DISP_ELEMS;

    // Record buffers (32MB each): A = d_out raw bytes, B = ws.
    f16x4* rA = (f16x4*)d_out;
    f16x4* rB = (f16x4*)d_ws;

    dim3 block(256);

    // INIT -> B (disp1, ldjac0)
    init_fused<<<dim3(TOT / 256), block, 0, stream>>>(vel, rB);

    // persistent cooperative kernel: 6 steps + final
    void* args[] = {(void*)&rA, (void*)&rB, (void*)&out, (void*)&lout};
    hipLaunchCooperativeKernel((const void*)integrate_coop, dim3(2048), block,
                               args, 0, stream);
}

// Round 14
// 174.490 us; speedup vs baseline: 9.8133x; 9.8133x over previous
//
#include <hip/hip_runtime.h>

// Integrator (scaling & squaring) for vel [16,2,512,512] f32, with logdet-Jacobian.
// ROUND-14 = round-11 structure (best, 127.9us) + init corner-select:
//   decoupled ldjac schedule: K_k streams disp_k, computes disp_{k+1} AND ldjac_k
//   with ONE shared sample position -> 8 parallel gathers, single dependent round.
//   fp16 disp interleaved [N,HW,2] + fp16 ldjac [N,HW]; XCD-remapped everywhere;
//   8 dispatches: INIT_FUSED -> 6x step_full -> FINAL.
// INIT: |eps*v| <= 0.05 px  =>  corner coords y0 in {y-1,y}, x0 in {x-1,x} are
//   PROVABLY inside the 3x3 sobel window -> corners come from registers (exact),
//   eliminating 8 gather loads/px in init.
// ws layout (48MB): dB 16MB | dC 16MB | lB 8MB | lA 8MB. d_out written only by FINAL.

#define NB 16
#define HH 512
#define WW 512
#define HW (HH * WW)          // 262144 = 1<<18
#define TOT (NB * HW)         // 4194304
#define EPS 0.0078125f        // 2^-7
#define DISP_ELEMS (NB * 2 * HW)   // 8388608 (f32 elems of final planar disp)
#define SC (512.0f / 511.0f)

typedef _Float16 f16;
typedef _Float16 f16x2 __attribute__((ext_vector_type(2)));

struct Samp {
    int i00, i01, i10, i11;   // clamped plane offsets (y*W+x)
    float w00, w01, w10, w11; // bilinear weights with OOB folded to 0
};

__device__ __forceinline__ Samp make_samp(float sy, float sx) {
    float fy = floorf(sy), fx = floorf(sx);
    float wy = sy - fy, wx = sx - fx;
    int y0 = (int)fy, x0 = (int)fx;
    int y1 = y0 + 1, x1 = x0 + 1;
    bool xv0 = (unsigned)x0 < (unsigned)WW;
    bool xv1 = (unsigned)x1 < (unsigned)WW;
    bool yv0 = (unsigned)y0 < (unsigned)HH;
    bool yv1 = (unsigned)y1 < (unsigned)HH;
    int xc0 = min(max(x0, 0), WW - 1), xc1 = min(max(x1, 0), WW - 1);
    int yc0 = min(max(y0, 0), HH - 1), yc1 = min(max(y1, 0), HH - 1);
    Samp s;
    s.i00 = yc0 * WW + xc0; s.i01 = yc0 * WW + xc1;
    s.i10 = yc1 * WW + xc0; s.i11 = yc1 * WW + xc1;
    float omwx = 1.0f - wx, omwy = 1.0f - wy;
    s.w00 = (xv0 && yv0) ? omwx * omwy : 0.0f;
    s.w01 = (xv1 && yv0) ? wx * omwy   : 0.0f;
    s.w10 = (xv0 && yv1) ? omwx * wy   : 0.0f;
    s.w11 = (xv1 && yv1) ? wx * wy     : 0.0f;
    return s;
}

// XCD-remapped index: XCD c (= bid&7 under round-robin dispatch) owns tasks
// [c*2048,(c+1)*2048) = images {2c,2c+1}, rows ascending.
__device__ __forceinline__ int remap_idx() {
    int bid = blockIdx.x;
    int task = ((bid & 7) << 11) | (bid >> 3);
    return task * 256 + threadIdx.x;
}

// emulate the fp16 store+load rounding of disp0 = eps*v
__device__ __forceinline__ float rnd16(float v) { return (float)(f16)v; }

// INIT_FUSED: ldjac0 (sobel logdet series) + disp1; bilerp corners of disp0
// selected from the in-register 3x3 window (exact; see header comment).
__global__ void __launch_bounds__(256) init_fused(const float* __restrict__ vel,
                                                  f16x2* __restrict__ ddst,
                                                  f16* __restrict__ ldst) {
    int idx = remap_idx();
    int n = idx >> 18;
    int rem = idx & (HW - 1);
    int y = rem >> 9, x = rem & (WW - 1);

    const float* v0 = vel + (size_t)n * 2 * HW;  // vel_y
    const float* v1 = v0 + HW;                   // vel_x

    // ---- 3x3 replicate-clamped window (both channels) ----
    int ym = max(y - 1, 0), yp = min(y + 1, HH - 1);
    int xm = max(x - 1, 0), xp = min(x + 1, WW - 1);
    int rows[3] = {ym * WW, y * WW, yp * WW};
    int cols[3] = {xm, x, xp};

    float A[3][3], B[3][3];
#pragma unroll
    for (int r = 0; r < 3; ++r)
#pragma unroll
        for (int c = 0; c < 3; ++c) {
            A[r][c] = v0[rows[r] + cols[c]];
            B[r][c] = v1[rows[r] + cols[c]];
        }

    // ---- sobel jacobian + logdet series (ldjac0) ----
    float a = 0.125f * ((A[2][0] + 2.0f * A[2][1] + A[2][2]) - (A[0][0] + 2.0f * A[0][1] + A[0][2]));
    float b = 0.125f * ((A[0][2] + 2.0f * A[1][2] + A[2][2]) - (A[0][0] + 2.0f * A[1][0] + A[2][0]));
    float c = 0.125f * ((B[2][0] + 2.0f * B[2][1] + B[2][2]) - (B[0][0] + 2.0f * B[0][1] + B[0][2]));
    float d = 0.125f * ((B[0][2] + 2.0f * B[1][2] + B[2][2]) - (B[0][0] + 2.0f * B[1][0] + B[2][0]));

    float xa = a, xb = b, xc = c, xd = d;
    float ld = EPS * (xa + xd);
    float na = xa * a + xb * c, nb = xa * b + xb * d;
    float nc = xc * a + xd * c, nd = xc * b + xd * d;
    xa = na; xb = nb; xc = nc; xd = nd;
    ld -= (EPS * EPS) * (xa + xd) * 0.5f;
    na = xa * a + xb * c; nb = xa * b + xb * d;
    nc = xc * a + xd * c; nd = xc * b + xd * d;
    xa = na; xb = nb; xc = nc; xd = nd;
    ld += (EPS * EPS * EPS) * (xa + xd) * (1.0f / 3.0f);
    na = xa * a + xb * c;
    nd = xc * b + xd * d;
    ld -= (EPS * EPS * EPS * EPS) * (na + nd) * 0.25f;

    ldst[(size_t)n * HW + rem] = (f16)ld;

    // ---- first disp step; corners selected from the window ----
    float d0 = rnd16(EPS * A[1][1]);
    float d1 = rnd16(EPS * B[1][1]);

    float sy = fmaf((float)y + d0, SC, -0.5f);
    float sx = fmaf((float)x + d1, SC, -0.5f);
    Samp s = make_samp(sy, sx);

    // y0 in {y-1, y}: row pair is (0,1) if y0<y else (1,2); same for x.
    // Clamping agrees with the window's replicate-clamp at image edges (exact).
    int rl = (sy < (float)y) ? 0 : 1;   // row of yc0 — y0<y  <=>  floor(sy)<y
    int cl = (sx < (float)x) ? 0 : 1;
    // NOTE: floor(sy)<y <=> sy<y for these ranges since y integer.
    int rhi = rl + 1, chi = cl + 1;

    float g00x = rnd16(EPS * A[rl][cl]),  g00y = rnd16(EPS * B[rl][cl]);
    float g01x = rnd16(EPS * A[rl][chi]), g01y = rnd16(EPS * B[rl][chi]);
    float g10x = rnd16(EPS * A[rhi][cl]), g10y = rnd16(EPS * B[rhi][cl]);
    float g11x = rnd16(EPS * A[rhi][chi]), g11y = rnd16(EPS * B[rhi][chi]);

    float nd0 = d0 + s.w00 * g00x + s.w01 * g01x + s.w10 * g10x + s.w11 * g11x;
    float nd1 = d1 + s.w00 * g00y + s.w01 * g01y + s.w10 * g10y + s.w11 * g11y;

    f16x2 w; w.x = (f16)nd0; w.y = (f16)nd1;
    ddst[(size_t)n * HW + rem] = w;
}

// K2..K7: disp_{k+1} AND ldjac_k, both sampled at phi(p, disp_k(p)) — one samp,
// 8 parallel gathers (4 disp + 4 ldjac), single dependent memory round.
__global__ void __launch_bounds__(256) step_full(const f16x2* __restrict__ dsrc,
                                                 const f16* __restrict__ lsrc,
                                                 f16x2* __restrict__ ddst,
                                                 f16* __restrict__ ldst) {
    int idx = remap_idx();
    int n = idx >> 18;
    int rem = idx & (HW - 1);
    int y = rem >> 9, x = rem & (WW - 1);

    const f16x2* dp = dsrc + (size_t)n * HW;
    const f16*   lp = lsrc + (size_t)n * HW;

    f16x2 dv = dp[rem];
    f16   lv = lp[rem];
    float d0 = (float)dv.x, d1 = (float)dv.y;

    float sy = fmaf((float)y + d0, SC, -0.5f);
    float sx = fmaf((float)x + d1, SC, -0.5f);
    Samp s = make_samp(sy, sx);

    f16x2 g00 = dp[s.i00], g01 = dp[s.i01], g10 = dp[s.i10], g11 = dp[s.i11];
    f16   h00 = lp[s.i00], h01 = lp[s.i01], h10 = lp[s.i10], h11 = lp[s.i11];

    float nd0 = d0 + s.w00 * (float)g00.x + s.w01 * (float)g01.x
                   + s.w10 * (float)g10.x + s.w11 * (float)g11.x;
    float nd1 = d1 + s.w00 * (float)g00.y + s.w01 * (float)g01.y
                   + s.w10 * (float)g10.y + s.w11 * (float)g11.y;
    float nl  = (float)lv + s.w00 * (float)h00 + s.w01 * (float)h01
                          + s.w10 * (float)h10 + s.w11 * (float)h11;

    f16x2 w; w.x = (f16)nd0; w.y = (f16)nd1;
    ddst[(size_t)n * HW + rem] = w;
    ldst[(size_t)n * HW + rem] = (f16)nl;
}

// FINAL: ldjac update #7 using streamed disp_7 (no disp gathers), plus planar
// f32 output of disp_7 and ldjac_7.
__global__ void __launch_bounds__(256) step_final(const f16x2* __restrict__ dsrc,
                                                  const f16* __restrict__ lsrc,
                                                  float* __restrict__ doutp,
                                                  float* __restrict__ loutp) {
    int idx = remap_idx();
    int n = idx >> 18;
    int rem = idx & (HW - 1);
    int y = rem >> 9, x = rem & (WW - 1);

    const f16x2* dp = dsrc + (size_t)n * HW;
    const f16*   lp = lsrc + (size_t)n * HW;

    f16x2 dv = dp[rem];
    f16   lv = lp[rem];
    float d0 = (float)dv.x, d1 = (float)dv.y;

    float sy = fmaf((float)y + d0, SC, -0.5f);
    float sx = fmaf((float)x + d1, SC, -0.5f);
    Samp s = make_samp(sy, sx);

    float nl = (float)lv + s.w00 * (float)lp[s.i00] + s.w01 * (float)lp[s.i01]
                         + s.w10 * (float)lp[s.i10] + s.w11 * (float)lp[s.i11];

    float* pd = doutp + (size_t)n * 2 * HW;
    pd[rem]      = d0;
    pd[HW + rem] = d1;
    loutp[(size_t)n * HW + rem] = nl;
}

extern "C" void kernel_launch(void* const* d_in, const int* in_sizes, int n_in,
                              void* d_out, int out_size, void* d_ws, size_t ws_size,
                              hipStream_t stream) {
    const float* vel = (const float*)d_in[0];
    float* out = (float*)d_out;

    // ws layout (48MB): dB 16MB | dC 16MB | lB 8MB | lA 8MB
    char* wsb = (char*)d_ws;
    f16x2* dB = (f16x2*)wsb;
    f16x2* dC = (f16x2*)(wsb + (size_t)16 * 1024 * 1024);
    f16*   lB = (f16*)  (wsb + (size_t)32 * 1024 * 1024);
    f16*   lA = (f16*)  (wsb + (size_t)40 * 1024 * 1024);

    dim3 grid(TOT / 256), block(256);     // 16384 blocks, 1 px/thread

    // INIT_FUSED -> (dC = disp1, lB = ldjac0)
    // K2: (dC,lB)->(dB,lA)  disp2, ldjac1
    // K3: (dB,lA)->(dC,lB)  disp3, ldjac2
    // K4: (dC,lB)->(dB,lA)  disp4, ldjac3
    // K5: (dB,lA)->(dC,lB)  disp5, ldjac4
    // K6: (dC,lB)->(dB,lA)  disp6, ldjac5
    // K7: (dB,lA)->(dC,lB)  disp7, ldjac6
    // FINAL: (dC,lB) -> d_out (planar f32 disp7 + f32 ldjac7)
    init_fused<<<grid, block, 0, stream>>>(vel, dC, lB);
    step_full<<<grid, block, 0, stream>>>(dC, lB, dB, lA);
    step_full<<<grid, block, 0, stream>>>(dB, lA, dC, lB);
    step_full<<<grid, block, 0, stream>>>(dC, lB, dB, lA);
    step_full<<<grid, block, 0, stream>>>(dB, lA, dC, lB);
    step_full<<<grid, block, 0, stream>>>(dC, lB, dB, lA);
    step_full<<<grid, block, 0, stream>>>(dB, lA, dC, lB);
    step_final<<<grid, block, 0, stream>>>(dC, lB, out, out + DISP_ELEMS);
}

// Round 15
// 128.395 us; speedup vs baseline: 13.3364x; 1.3590x over previous
//
#include <hip/hip_runtime.h>

// Integrator (scaling & squaring) for vel [16,2,512,512] f32, with logdet-Jacobian.
// ROUND-15 = round-11 structure + init corner-select with STATIC indexing
// (round-14's runtime-indexed window spilled to LDS/scratch: 72us init,
// LDS_Block_Size=18432, 142K bank conflicts; fixed with branchless ternaries
// over compile-time indices -> pure v_cndmask, window stays in VGPRs).
//   Decoupled ldjac schedule: K_k streams disp_k, computes disp_{k+1} AND ldjac_k
//   with ONE shared sample position -> 8 parallel gathers, single dependent round.
//   fp16 disp interleaved [N,HW,2] + fp16 ldjac [N,HW]; XCD-remapped everywhere;
//   8 dispatches: INIT_FUSED -> 6x step_full -> FINAL.
// ws layout (48MB): dB 16MB | dC 16MB | lB 8MB | lA 8MB. d_out written only by FINAL.

#define NB 16
#define HH 512
#define WW 512
#define HW (HH * WW)          // 262144 = 1<<18
#define TOT (NB * HW)         // 4194304
#define EPS 0.0078125f        // 2^-7
#define DISP_ELEMS (NB * 2 * HW)   // 8388608 (f32 elems of final planar disp)
#define SC (512.0f / 511.0f)

typedef _Float16 f16;
typedef _Float16 f16x2 __attribute__((ext_vector_type(2)));

struct Samp {
    int i00, i01, i10, i11;   // clamped plane offsets (y*W+x)
    float w00, w01, w10, w11; // bilinear weights with OOB folded to 0
};

__device__ __forceinline__ Samp make_samp(float sy, float sx) {
    float fy = floorf(sy), fx = floorf(sx);
    float wy = sy - fy, wx = sx - fx;
    int y0 = (int)fy, x0 = (int)fx;
    int y1 = y0 + 1, x1 = x0 + 1;
    bool xv0 = (unsigned)x0 < (unsigned)WW;
    bool xv1 = (unsigned)x1 < (unsigned)WW;
    bool yv0 = (unsigned)y0 < (unsigned)HH;
    bool yv1 = (unsigned)y1 < (unsigned)HH;
    int xc0 = min(max(x0, 0), WW - 1), xc1 = min(max(x1, 0), WW - 1);
    int yc0 = min(max(y0, 0), HH - 1), yc1 = min(max(y1, 0), HH - 1);
    Samp s;
    s.i00 = yc0 * WW + xc0; s.i01 = yc0 * WW + xc1;
    s.i10 = yc1 * WW + xc0; s.i11 = yc1 * WW + xc1;
    float omwx = 1.0f - wx, omwy = 1.0f - wy;
    s.w00 = (xv0 && yv0) ? omwx * omwy : 0.0f;
    s.w01 = (xv1 && yv0) ? wx * omwy   : 0.0f;
    s.w10 = (xv0 && yv1) ? omwx * wy   : 0.0f;
    s.w11 = (xv1 && yv1) ? wx * wy     : 0.0f;
    return s;
}

// XCD-remapped index: XCD c (= bid&7 under round-robin dispatch) owns tasks
// [c*2048,(c+1)*2048) = images {2c,2c+1}, rows ascending.
__device__ __forceinline__ int remap_idx() {
    int bid = blockIdx.x;
    int task = ((bid & 7) << 11) | (bid >> 3);
    return task * 256 + threadIdx.x;
}

// emulate the fp16 store+load rounding of disp0 = eps*v
__device__ __forceinline__ float rnd16(float v) { return (float)(f16)v; }

// INIT_FUSED: ldjac0 (sobel logdet series) + disp1; bilerp corners of disp0
// selected from the in-register 3x3 window via static-index cndmask chains.
// (|eps*v| <= ~0.05 px => corner coords y0 in {y-1,y}, x0 in {x-1,x}, always
// inside the window; replicate-clamp of the window matches bilerp clamping.)
__global__ void __launch_bounds__(256) init_fused(const float* __restrict__ vel,
                                                  f16x2* __restrict__ ddst,
                                                  f16* __restrict__ ldst) {
    int idx = remap_idx();
    int n = idx >> 18;
    int rem = idx & (HW - 1);
    int y = rem >> 9, x = rem & (WW - 1);

    const float* v0 = vel + (size_t)n * 2 * HW;  // vel_y
    const float* v1 = v0 + HW;                   // vel_x

    // ---- 3x3 replicate-clamped window (both channels), static indices only ----
    int ym = max(y - 1, 0), yp = min(y + 1, HH - 1);
    int xm = max(x - 1, 0), xp = min(x + 1, WW - 1);
    int r0 = ym * WW, r1 = y * WW, r2 = yp * WW;

    float A00 = v0[r0 + xm], A01 = v0[r0 + x], A02 = v0[r0 + xp];
    float A10 = v0[r1 + xm], A11 = v0[r1 + x], A12 = v0[r1 + xp];
    float A20 = v0[r2 + xm], A21 = v0[r2 + x], A22 = v0[r2 + xp];
    float B00 = v1[r0 + xm], B01 = v1[r0 + x], B02 = v1[r0 + xp];
    float B10 = v1[r1 + xm], B11 = v1[r1 + x], B12 = v1[r1 + xp];
    float B20 = v1[r2 + xm], B21 = v1[r2 + x], B22 = v1[r2 + xp];

    // ---- sobel jacobian + logdet series (ldjac0) ----
    float a = 0.125f * ((A20 + 2.0f * A21 + A22) - (A00 + 2.0f * A01 + A02));
    float b = 0.125f * ((A02 + 2.0f * A12 + A22) - (A00 + 2.0f * A10 + A20));
    float c = 0.125f * ((B20 + 2.0f * B21 + B22) - (B00 + 2.0f * B01 + B02));
    float d = 0.125f * ((B02 + 2.0f * B12 + B22) - (B00 + 2.0f * B10 + B20));

    float xa = a, xb = b, xc = c, xd = d;
    float ld = EPS * (xa + xd);
    float na = xa * a + xb * c, nb = xa * b + xb * d;
    float nc = xc * a + xd * c, nd = xc * b + xd * d;
    xa = na; xb = nb; xc = nc; xd = nd;
    ld -= (EPS * EPS) * (xa + xd) * 0.5f;
    na = xa * a + xb * c; nb = xa * b + xb * d;
    nc = xc * a + xd * c; nd = xc * b + xd * d;
    xa = na; xb = nb; xc = nc; xd = nd;
    ld += (EPS * EPS * EPS) * (xa + xd) * (1.0f / 3.0f);
    na = xa * a + xb * c;
    nd = xc * b + xd * d;
    ld -= (EPS * EPS * EPS * EPS) * (na + nd) * 0.25f;

    ldst[(size_t)n * HW + rem] = (f16)ld;

    // ---- first disp step; corners selected from the window (static idx) ----
    float d0 = rnd16(EPS * A11);
    float d1 = rnd16(EPS * B11);

    float sy = fmaf((float)y + d0, SC, -0.5f);
    float sx = fmaf((float)x + d1, SC, -0.5f);
    Samp s = make_samp(sy, sx);

    bool rlo = (sy < (float)y);   // floor(sy) == y-1  (else y)
    bool clo = (sx < (float)x);   // floor(sx) == x-1  (else x)

    // row-pair select (static indices; rlo -> rows {0,1}, else {1,2})
    float Ar0c0 = rlo ? A00 : A10, Ar0c1 = rlo ? A01 : A11, Ar0c2 = rlo ? A02 : A12;
    float Ar1c0 = rlo ? A10 : A20, Ar1c1 = rlo ? A11 : A21, Ar1c2 = rlo ? A12 : A22;
    float Br0c0 = rlo ? B00 : B10, Br0c1 = rlo ? B01 : B11, Br0c2 = rlo ? B02 : B12;
    float Br1c0 = rlo ? B10 : B20, Br1c1 = rlo ? B11 : B21, Br1c2 = rlo ? B12 : B22;

    // column-pair select (clo -> cols {0,1}, else {1,2})
    float g00x = rnd16(EPS * (clo ? Ar0c0 : Ar0c1));
    float g01x = rnd16(EPS * (clo ? Ar0c1 : Ar0c2));
    float g10x = rnd16(EPS * (clo ? Ar1c0 : Ar1c1));
    float g11x = rnd16(EPS * (clo ? Ar1c1 : Ar1c2));
    float g00y = rnd16(EPS * (clo ? Br0c0 : Br0c1));
    float g01y = rnd16(EPS * (clo ? Br0c1 : Br0c2));
    float g10y = rnd16(EPS * (clo ? Br1c0 : Br1c1));
    float g11y = rnd16(EPS * (clo ? Br1c1 : Br1c2));

    float nd0 = d0 + s.w00 * g00x + s.w01 * g01x + s.w10 * g10x + s.w11 * g11x;
    float nd1 = d1 + s.w00 * g00y + s.w01 * g01y + s.w10 * g10y + s.w11 * g11y;

    f16x2 w; w.x = (f16)nd0; w.y = (f16)nd1;
    ddst[(size_t)n * HW + rem] = w;
}

// K2..K7: disp_{k+1} AND ldjac_k, both sampled at phi(p, disp_k(p)) — one samp,
// 8 parallel gathers (4 disp + 4 ldjac), single dependent memory round.
__global__ void __launch_bounds__(256) step_full(const f16x2* __restrict__ dsrc,
                                                 const f16* __restrict__ lsrc,
                                                 f16x2* __restrict__ ddst,
                                                 f16* __restrict__ ldst) {
    int idx = remap_idx();
    int n = idx >> 18;
    int rem = idx & (HW - 1);
    int y = rem >> 9, x = rem & (WW - 1);

    const f16x2* dp = dsrc + (size_t)n * HW;
    const f16*   lp = lsrc + (size_t)n * HW;

    f16x2 dv = dp[rem];
    f16   lv = lp[rem];
    float d0 = (float)dv.x, d1 = (float)dv.y;

    float sy = fmaf((float)y + d0, SC, -0.5f);
    float sx = fmaf((float)x + d1, SC, -0.5f);
    Samp s = make_samp(sy, sx);

    f16x2 g00 = dp[s.i00], g01 = dp[s.i01], g10 = dp[s.i10], g11 = dp[s.i11];
    f16   h00 = lp[s.i00], h01 = lp[s.i01], h10 = lp[s.i10], h11 = lp[s.i11];

    float nd0 = d0 + s.w00 * (float)g00.x + s.w01 * (float)g01.x
                   + s.w10 * (float)g10.x + s.w11 * (float)g11.x;
    float nd1 = d1 + s.w00 * (float)g00.y + s.w01 * (float)g01.y
                   + s.w10 * (float)g10.y + s.w11 * (float)g11.y;
    float nl  = (float)lv + s.w00 * (float)h00 + s.w01 * (float)h01
                          + s.w10 * (float)h10 + s.w11 * (float)h11;

    f16x2 w; w.x = (f16)nd0; w.y = (f16)nd1;
    ddst[(size_t)n * HW + rem] = w;
    ldst[(size_t)n * HW + rem] = (f16)nl;
}

// FINAL: ldjac update #7 using streamed disp_7 (no disp gathers), plus planar
// f32 output of disp_7 and ldjac_7.
__global__ void __launch_bounds__(256) step_final(const f16x2* __restrict__ dsrc,
                                                  const f16* __restrict__ lsrc,
                                                  float* __restrict__ doutp,
                                                  float* __restrict__ loutp) {
    int idx = remap_idx();
    int n = idx >> 18;
    int rem = idx & (HW - 1);
    int y = rem >> 9, x = rem & (WW - 1);

    const f16x2* dp = dsrc + (size_t)n * HW;
    const f16*   lp = lsrc + (size_t)n * HW;

    f16x2 dv = dp[rem];
    f16   lv = lp[rem];
    float d0 = (float)dv.x, d1 = (float)dv.y;

    float sy = fmaf((float)y + d0, SC, -0.5f);
    float sx = fmaf((float)x + d1, SC, -0.5f);
    Samp s = make_samp(sy, sx);

    float nl = (float)lv + s.w00 * (float)lp[s.i00] + s.w01 * (float)lp[s.i01]
                         + s.w10 * (float)lp[s.i10] + s.w11 * (float)lp[s.i11];

    float* pd = doutp + (size_t)n * 2 * HW;
    pd[rem]      = d0;
    pd[HW + rem] = d1;
    loutp[(size_t)n * HW + rem] = nl;
}

extern "C" void kernel_launch(void* const* d_in, const int* in_sizes, int n_in,
                              void* d_out, int out_size, void* d_ws, size_t ws_size,
                              hipStream_t stream) {
    const float* vel = (const float*)d_in[0];
    float* out = (float*)d_out;

    // ws layout (48MB): dB 16MB | dC 16MB | lB 8MB | lA 8MB
    char* wsb = (char*)d_ws;
    f16x2* dB = (f16x2*)wsb;
    f16x2* dC = (f16x2*)(wsb + (size_t)16 * 1024 * 1024);
    f16*   lB = (f16*)  (wsb + (size_t)32 * 1024 * 1024);
    f16*   lA = (f16*)  (wsb + (size_t)40 * 1024 * 1024);

    dim3 grid(TOT / 256), block(256);     // 16384 blocks, 1 px/thread

    // INIT_FUSED -> (dC = disp1, lB = ldjac0)
    // K2: (dC,lB)->(dB,lA)  disp2, ldjac1
    // K3: (dB,lA)->(dC,lB)  disp3, ldjac2
    // K4: (dC,lB)->(dB,lA)  disp4, ldjac3
    // K5: (dB,lA)->(dC,lB)  disp5, ldjac4
    // K6: (dC,lB)->(dB,lA)  disp6, ldjac5
    // K7: (dB,lA)->(dC,lB)  disp7, ldjac6
    // FINAL: (dC,lB) -> d_out (planar f32 disp7 + f32 ldjac7)
    init_fused<<<grid, block, 0, stream>>>(vel, dC, lB);
    step_full<<<grid, block, 0, stream>>>(dC, lB, dB, lA);
    step_full<<<grid, block, 0, stream>>>(dB, lA, dC, lB);
    step_full<<<grid, block, 0, stream>>>(dC, lB, dB, lA);
    step_full<<<grid, block, 0, stream>>>(dB, lA, dC, lB);
    step_full<<<grid, block, 0, stream>>>(dC, lB, dB, lA);
    step_full<<<grid, block, 0, stream>>>(dB, lA, dC, lB);
    step_final<<<grid, block, 0, stream>>>(dC, lB, out, out + DISP_ELEMS);
}